// Round 1
// baseline (751.446 us; speedup 1.0000x reference)
//
#include <hip/hip_runtime.h>

// JunctionPoolModule: per-junction segment min/max over edge_features rows.
// edge_features: (E, 64) fp32; cell_0_bounds: (J, 2) int32 [start, end).
// out: (J, 128) fp32 = concat(mins(64), maxs(64)).
//
// Layout: 16 threads per junction, each owns 4 channels (float4).
// Each edge row = 64 fp32 = 16 float4 -> one 256B coalesced read per row.
// Output: two 256B coalesced float4 writes per junction.

#define THREADS_PER_J 16

__global__ void __launch_bounds__(256)
junction_pool_kernel(const float* __restrict__ edge_features,
                     const int*   __restrict__ bounds,
                     float*       __restrict__ out,
                     int n_junctions)
{
    const long long tid = (long long)blockIdx.x * blockDim.x + threadIdx.x;
    const int j  = (int)(tid >> 4);   // junction index
    const int cg = (int)(tid & 15);   // channel group (4 channels)
    if (j >= n_junctions) return;

    const int start = bounds[2 * j];
    const int end   = bounds[2 * j + 1];

    const float inf = __builtin_inff();
    float4 mn = make_float4( inf,  inf,  inf,  inf);
    float4 mx = make_float4(-inf, -inf, -inf, -inf);

    const float4* __restrict__ ef = reinterpret_cast<const float4*>(edge_features);
    // edge row e occupies float4 slots [e*16, e*16+16); this thread reads slot e*16+cg
    for (int e = start; e < end; ++e) {
        float4 v = ef[(long long)e * 16 + cg];
        mn.x = fminf(mn.x, v.x); mn.y = fminf(mn.y, v.y);
        mn.z = fminf(mn.z, v.z); mn.w = fminf(mn.w, v.w);
        mx.x = fmaxf(mx.x, v.x); mx.y = fmaxf(mx.y, v.y);
        mx.z = fmaxf(mx.z, v.z); mx.w = fmaxf(mx.w, v.w);
    }

    // out row j: 128 floats = 32 float4. mins at [0,16), maxs at [16,32).
    float4* __restrict__ o = reinterpret_cast<float4*>(out);
    o[(long long)j * 32 + cg]      = mn;
    o[(long long)j * 32 + 16 + cg] = mx;
}

extern "C" void kernel_launch(void* const* d_in, const int* in_sizes, int n_in,
                              void* d_out, int out_size, void* d_ws, size_t ws_size,
                              hipStream_t stream)
{
    const float* edge_features = (const float*)d_in[0];
    const int*   bounds        = (const int*)d_in[1];
    float*       out           = (float*)d_out;

    const int n_junctions = in_sizes[1] / 2;        // (J, 2) int32
    const long long total_threads = (long long)n_junctions * THREADS_PER_J;
    const int block = 256;
    const int grid  = (int)((total_threads + block - 1) / block);

    junction_pool_kernel<<<grid, block, 0, stream>>>(edge_features, bounds, out, n_junctions);
}

// Round 2
// 748.868 us; speedup vs baseline: 1.0034x; 1.0034x over previous
//
#include <hip/hip_runtime.h>

// JunctionPoolModule: per-junction segment min/max over edge_features rows.
// edge_features: (E, 64) fp32; cell_0_bounds: (J, 2) int32 [start, end).
// out: (J, 128) fp32 = concat(mins(64), maxs(64)).
//
// Layout: 16 threads per junction, each owns 4 channels (float4 = 16 B/lane).
// Segment lengths follow the pattern {1,3,4,8} (max 8), so we issue 8
// UNCONDITIONAL independent loads per thread with the row index clamped to
// the last valid row (duplicates are harmless for min/max and hit cache).
// This gives 8x memory-level parallelism vs. the dynamic loop (which
// serialized load->waitcnt->reduce per iteration) and removes all control
// divergence. A tail loop covers the (never-taken here) len > 8 case.

#define THREADS_PER_J 16
#define MAX_UNROLL 8

__global__ void __launch_bounds__(256)
junction_pool_kernel(const float4* __restrict__ ef,
                     const int2*   __restrict__ bounds,
                     float4*       __restrict__ out,
                     int n_junctions)
{
    const long long tid = (long long)blockIdx.x * blockDim.x + threadIdx.x;
    const int j  = (int)(tid >> 4);   // junction index
    const int cg = (int)(tid & 15);   // channel group (4 channels)
    if (j >= n_junctions) return;

    const int2 se   = bounds[j];
    const int start = se.x;
    const int end   = se.y;
    const int len   = end - start;          // >= 1 for this problem
    const int lm1   = (len > 0) ? (len - 1) : 0;

    // Base float4 slot for this thread: row `start`, channel group cg.
    const float4* __restrict__ base = ef + (long long)start * 16 + cg;

    // Issue all 8 loads independently (clamped index -> no branches).
    float4 v[MAX_UNROLL];
    #pragma unroll
    for (int k = 0; k < MAX_UNROLL; ++k) {
        const int off = (k < lm1) ? k : lm1;   // min(k, len-1)
        v[k] = base[(long long)off * 16];
    }

    float4 mn = v[0];
    float4 mx = v[0];
    #pragma unroll
    for (int k = 1; k < MAX_UNROLL; ++k) {
        mn.x = fminf(mn.x, v[k].x); mn.y = fminf(mn.y, v[k].y);
        mn.z = fminf(mn.z, v[k].z); mn.w = fminf(mn.w, v[k].w);
        mx.x = fmaxf(mx.x, v[k].x); mx.y = fmaxf(mx.y, v[k].y);
        mx.z = fmaxf(mx.z, v[k].z); mx.w = fmaxf(mx.w, v[k].w);
    }

    // Safety tail for segments longer than MAX_UNROLL (not taken on this data).
    for (int e = start + MAX_UNROLL; e < end; ++e) {
        const float4 w = ef[(long long)e * 16 + cg];
        mn.x = fminf(mn.x, w.x); mn.y = fminf(mn.y, w.y);
        mn.z = fminf(mn.z, w.z); mn.w = fminf(mn.w, w.w);
        mx.x = fmaxf(mx.x, w.x); mx.y = fmaxf(mx.y, w.y);
        mx.z = fmaxf(mx.z, w.z); mx.w = fmaxf(mx.w, w.w);
    }

    // out row j: 128 floats = 32 float4. mins at [0,16), maxs at [16,32).
    out[(long long)j * 32 + cg]      = mn;
    out[(long long)j * 32 + 16 + cg] = mx;
}

extern "C" void kernel_launch(void* const* d_in, const int* in_sizes, int n_in,
                              void* d_out, int out_size, void* d_ws, size_t ws_size,
                              hipStream_t stream)
{
    const float4* edge_features = (const float4*)d_in[0];
    const int2*   bounds        = (const int2*)d_in[1];
    float4*       out           = (float4*)d_out;

    const int n_junctions = in_sizes[1] / 2;        // (J, 2) int32
    const long long total_threads = (long long)n_junctions * THREADS_PER_J;
    const int block = 256;
    const int grid  = (int)((total_threads + block - 1) / block);

    junction_pool_kernel<<<grid, block, 0, stream>>>(edge_features, bounds, out, n_junctions);
}